// Round 9
// baseline (160.146 us; speedup 1.0000x reference)
//
#include <hip/hip_runtime.h>

// ---------------------------------------------------------------------------
// Joint network: y = relu(f@W1t^T + g@W1p^T + (b1t+b1p)) @ W2^T + b2
// N=32768, K1=1344 (1024 f + 320 g), J=512, KOUT=29. fp32 in/out, bf16 MFMA.
// R9: ZERO-BARRIER K-loop. No LDS in phase 1 at all. Each wave loads its
//     own A (global fp32 -> reg -> bf16) and B (L2 -> reg, nontemporal,
//     transient). Waves free-run; TLP at 4 waves/SIMD does the pipelining.
//     Phase 2 (h @ W2^T) keeps the verified R5 LDS-chunk structure.
// ---------------------------------------------------------------------------

typedef float  f32x4  __attribute__((ext_vector_type(4)));
typedef short  s16x8  __attribute__((ext_vector_type(8)));   // 8 bf16

#define N_ROWS   32768
#define KOUT     29

#define WC_ELEMS   (42 * 4 * 512 * 8)    // 688128 bf16: [ks][kc][j][8]
#define W2C_ELEMS  (64 * 32 * 8)         // 16384 bf16:  [jc][kout32][8]

static __device__ __forceinline__ unsigned short f2bf(float x) {
  union { float f; unsigned u; } v; v.f = x;
  unsigned r = v.u + 0x7fffu + ((v.u >> 16) & 1u);   // RNE
  return (unsigned short)(r >> 16);
}

static __device__ __forceinline__ s16x8 cvt8(const f32x4 a, const f32x4 b) {
  s16x8 r;
  r[0] = (short)f2bf(a[0]); r[1] = (short)f2bf(a[1]);
  r[2] = (short)f2bf(a[2]); r[3] = (short)f2bf(a[3]);
  r[4] = (short)f2bf(b[0]); r[5] = (short)f2bf(b[1]);
  r[6] = (short)f2bf(b[2]); r[7] = (short)f2bf(b[3]);
  return r;
}

// ---------------------------------------------------------------------------
__global__ __launch_bounds__(512) void prep_kernel(
    const float* __restrict__ W1t, const float* __restrict__ b1t,
    const float* __restrict__ W1p, const float* __restrict__ b1p,
    const float* __restrict__ W2,  const float* __restrict__ b2,
    unsigned short* __restrict__ Wc, unsigned short* __restrict__ W2c,
    float* __restrict__ bc, float* __restrict__ b2c) {
  int idx = blockIdx.x * 512 + threadIdx.x;
  if (idx < WC_ELEMS) {
    int e  = idx & 7;
    int j  = (idx >> 3) & 511;
    int kc = (idx >> 12) & 3;
    int ks = idx >> 14;
    int c  = ks * 32 + kc * 8 + e;
    float v = (c < 1024) ? W1t[j * 1024 + c] : W1p[j * 320 + (c - 1024)];
    Wc[idx] = f2bf(v);
  }
  if (idx < W2C_ELEMS) {
    int e  = idx & 7;
    int ko = (idx >> 3) & 31;
    int jc = idx >> 8;
    int j  = jc * 8 + e;
    float v = (ko < KOUT) ? W2[ko * 512 + j] : 0.0f;
    W2c[idx] = f2bf(v);
  }
  if (idx < 512) bc[idx]  = b1t[idx] + b1p[idx];
  if (idx < 32)  b2c[idx] = (idx < KOUT) ? b2[idx] : 0.0f;
}

// ---------------------------------------------------------------------------
// 512 blocks x 512 threads (8 waves, 2 blocks/CU, 4 waves/SIMD).
// Block tile 64 x 512. Wave w: wm=w>>2 rows wm*32+[0,32), wn=w&3 cols
// wn*128+[0,128): acc[2][8] (64 f32 -> AGPR).
// Phase 1: NO LDS, NO barriers. Phase 2: 16 KB LDS h-chunks (R5 structure).
// ---------------------------------------------------------------------------
__global__ __launch_bounds__(512, 4) void joint_kernel(
    const float* __restrict__ f, const float* __restrict__ g,
    const unsigned short* __restrict__ Wc, const unsigned short* __restrict__ W2c,
    const float* __restrict__ bc, const float* __restrict__ b2c,
    float* __restrict__ out) {
  __shared__ __align__(16) char smem[16384];

  const int tid = threadIdx.x;
  const int l   = tid & 63;
  const int w   = tid >> 6;          // wave 0..7
  const int wm  = w >> 2;            // 0..1 (rows wm*32)
  const int wn  = w & 3;             // 0..3 (cols wn*128)
  const int m0  = blockIdx.x * 64;

  const int kcg = l >> 4;            // 0..3
  const int lc  = l & 15;

  // A bases: frag row = m0 + wm*32 + mi*16 + lc, k = T*32 + kcg*8 + e
  const char* fb0 = (const char*)f + (size_t)(m0 + wm * 32 + lc) * 4096 + kcg * 32;
  const char* fb1 = fb0 + 16 * 4096;
  const char* gb0 = (const char*)g + (size_t)(m0 + wm * 32 + lc) * 1280 + kcg * 32;
  const char* gb1 = gb0 + 16 * 1280;
  // B base: j = wn*128 + n*16 + lc, k-chunk kcg; frag n at +n*256, step +32768
  const char* WbT = (const char*)Wc + kcg * 8192 + (wn * 128 + lc) * 16;

  f32x4 acc[2][8];
#pragma unroll
  for (int m = 0; m < 2; m++)
#pragma unroll
    for (int n = 0; n < 8; n++) acc[m][n] = (f32x4)(0.0f);

#define K_BODY(PA0, PA1, PB) {                                              \
    f32x4 a00 = *(const f32x4*)(PA0);                                       \
    f32x4 a01 = *(const f32x4*)((PA0) + 16);                                \
    f32x4 a10 = *(const f32x4*)(PA1);                                       \
    f32x4 a11 = *(const f32x4*)((PA1) + 16);                                \
    s16x8 bq0[4];                                                           \
    _Pragma("unroll")                                                       \
    for (int n = 0; n < 4; n++)                                             \
      bq0[n] = __builtin_nontemporal_load((const s16x8*)((PB) + n * 256));  \
    s16x8 af0 = cvt8(a00, a01);                                             \
    s16x8 af1 = cvt8(a10, a11);                                             \
    s16x8 bq1[4];                                                           \
    _Pragma("unroll")                                                       \
    for (int n = 0; n < 4; n++)                                             \
      bq1[n] = __builtin_nontemporal_load((const s16x8*)((PB) + 1024 + n * 256)); \
    _Pragma("unroll")                                                       \
    for (int n = 0; n < 4; n++) {                                           \
      acc[0][n] = __builtin_amdgcn_mfma_f32_16x16x32_bf16(af0, bq0[n],      \
                                                          acc[0][n], 0, 0, 0); \
      acc[1][n] = __builtin_amdgcn_mfma_f32_16x16x32_bf16(af1, bq0[n],      \
                                                          acc[1][n], 0, 0, 0); \
    }                                                                       \
    _Pragma("unroll")                                                       \
    for (int n = 0; n < 4; n++) {                                           \
      acc[0][4 + n] = __builtin_amdgcn_mfma_f32_16x16x32_bf16(af0, bq1[n],  \
                                                          acc[0][4 + n], 0, 0, 0); \
      acc[1][4 + n] = __builtin_amdgcn_mfma_f32_16x16x32_bf16(af1, bq1[n],  \
                                                          acc[1][4 + n], 0, 0, 0); \
    }                                                                       \
  }

  // ---- K loop: T=0..31 from f, T=32..41 from g. No barriers, no LDS. ----
#pragma unroll 2
  for (int T = 0; T < 32; ++T) {
    K_BODY(fb0 + (size_t)T * 128, fb1 + (size_t)T * 128,
           WbT + (size_t)T * 32768);
  }
#pragma unroll 2
  for (int T2 = 0; T2 < 10; ++T2) {
    K_BODY(gb0 + (size_t)T2 * 128, gb1 + (size_t)T2 * 128,
           WbT + (size_t)(32 + T2) * 32768);
  }
#undef K_BODY

  // ---- phase 2: y = relu(h+bias) @ W2^T + b2, h streamed in 4 chunks ----
  // Chunk p: cols [p*128,(p+1)*128), written by the 2 waves with wn==p
  // (wm 0,1 -> rows 0..63). Then all 8 waves MFMA: wave w owns y rows
  // (w&3)*16.., ko (w>>2)*16.. W2 read from L2 (W2c).
  float bias[8];
#pragma unroll
  for (int n = 0; n < 8; n++) bias[n] = bc[wn * 128 + n * 16 + lc];

  f32x4 acc2 = (f32x4)(0.0f);
  const int ko = (w >> 2) * 16 + lc;
  const unsigned h_rdrow = (unsigned)(((w & 3) * 16 + lc) * 16);

#pragma unroll
  for (int p = 0; p < 4; p++) {
    __syncthreads();                 // h chunk region free
    if (wn == p) {
#pragma unroll
      for (int n = 0; n < 8; n++) {
        const int jrel  = n * 16 + lc;           // 0..127
        const int plane = jrel >> 3;             // 0..15
        const unsigned wswz = (unsigned)((plane & 3) << 5);
#pragma unroll
        for (int m = 0; m < 2; m++)
#pragma unroll
          for (int r = 0; r < 4; r++) {
            float v = fmaxf(acc[m][n][r] + bias[n], 0.0f);
            const unsigned rowh = (unsigned)(wm * 32 + m * 16 + kcg * 4 + r);
            *(unsigned short*)(smem + plane * 1024 +
                ((rowh * 16 + (jrel & 7) * 2) ^ wswz)) = f2bf(v);
          }
      }
    }
    __syncthreads();
    s16x8 wfv[4];
#pragma unroll
    for (int ks2 = 0; ks2 < 4; ks2++)
      wfv[ks2] = *(const s16x8*)((const char*)W2c +
                   (p * 16 + ks2 * 4 + kcg) * 512 + ko * 16);
#pragma unroll
    for (int ks2 = 0; ks2 < 4; ks2++) {
      const int plane = ks2 * 4 + kcg;
      s16x8 hf = *(const s16x8*)(smem + plane * 1024 +
                                 (h_rdrow ^ ((unsigned)(plane & 3) << 5)));
      acc2 = __builtin_amdgcn_mfma_f32_16x16x32_bf16(hf, wfv[ks2], acc2, 0, 0, 0);
    }
  }

  // ---- epilogue: +b2, store (29 of 32 cols) ----
  if (ko < KOUT) {
    const float bb = b2c[ko];
    const int orow0 = m0 + (w & 3) * 16 + kcg * 4;
#pragma unroll
    for (int r = 0; r < 4; r++)
      out[(size_t)(orow0 + r) * KOUT + ko] = acc2[r] + bb;
  }
}

// ---------------------------------------------------------------------------
extern "C" void kernel_launch(void* const* d_in, const int* in_sizes, int n_in,
                              void* d_out, int out_size, void* d_ws, size_t ws_size,
                              hipStream_t stream) {
  const float* f   = (const float*)d_in[0];
  const float* g   = (const float*)d_in[1];
  const float* W1t = (const float*)d_in[2];
  const float* b1t = (const float*)d_in[3];
  const float* W1p = (const float*)d_in[4];
  const float* b1p = (const float*)d_in[5];
  const float* W2  = (const float*)d_in[6];
  const float* b2  = (const float*)d_in[7];
  float* out = (float*)d_out;

  unsigned short* Wc  = (unsigned short*)d_ws;
  unsigned short* W2c = Wc + WC_ELEMS;
  float* bcp  = (float*)(W2c + W2C_ELEMS);
  float* b2cp = bcp + 512;

  prep_kernel<<<WC_ELEMS / 512, 512, 0, stream>>>(W1t, b1t, W1p, b1p, W2, b2,
                                                  Wc, W2c, bcp, b2cp);
  joint_kernel<<<N_ROWS / 64, 512, 0, stream>>>(f, g, Wc, W2c, bcp, b2cp, out);
}

// Round 10
// 83.133 us; speedup vs baseline: 1.9264x; 1.9264x over previous
//
#include <hip/hip_runtime.h>

// ---------------------------------------------------------------------------
// Joint network: y = relu(f@W1t^T + g@W1p^T + (b1t+b1p)) @ W2^T + b2
// N=32768, K1=1344 (1024 f + 320 g), J=512, KOUT=29. fp32 in/out, bf16 MFMA.
// R10: faithful m201-style phase interleave. BM=128, BN=512, 8 waves,
//      1 block/CU. Per K-step(32): 2 barrier-paired phases x 16 MFMA with
//      fine {gls | A-write | ds_read} interleave, counted VMCNT(2)/step,
//      setprio around MFMA. A reg-staged (T14 split), B gls dbuf.
// ---------------------------------------------------------------------------

typedef float  f32x4  __attribute__((ext_vector_type(4)));
typedef short  s16x8  __attribute__((ext_vector_type(8)));   // 8 bf16
typedef short  s16x4  __attribute__((ext_vector_type(4)));   // 4 bf16

#define N_ROWS   32768
#define KOUT     29

#define WC_ELEMS   (42 * 4 * 512 * 8)    // 688128 bf16: [ks][kc][j=512][8]
#define W2C_ELEMS  (64 * 32 * 8)         // 16384 bf16:  [jc][ko32][8]

#define VMCNT(n)   asm volatile("s_waitcnt vmcnt(" #n ")" ::: "memory")
#define LGKM0()    asm volatile("s_waitcnt lgkmcnt(0)" ::: "memory")
#define SBAR()     __builtin_amdgcn_s_barrier()
#define PRIO(n)    __builtin_amdgcn_s_setprio(n)

typedef const __attribute__((address_space(1))) unsigned int* gp_t;
typedef __attribute__((address_space(3))) unsigned int* lp_t;

static __device__ __forceinline__ void gls16(const void* g, void* l) {
  __builtin_amdgcn_global_load_lds((gp_t)g, (lp_t)l, 16, 0, 0);
}

static __device__ __forceinline__ unsigned short f2bf(float x) {
  union { float f; unsigned u; } v; v.f = x;
  unsigned r = v.u + 0x7fffu + ((v.u >> 16) & 1u);   // RNE
  return (unsigned short)(r >> 16);
}

// ---------------------------------------------------------------------------
__global__ __launch_bounds__(512) void prep_kernel(
    const float* __restrict__ W1t, const float* __restrict__ b1t,
    const float* __restrict__ W1p, const float* __restrict__ b1p,
    const float* __restrict__ W2,  const float* __restrict__ b2,
    unsigned short* __restrict__ Wc, unsigned short* __restrict__ W2c,
    float* __restrict__ bc, float* __restrict__ b2c) {
  int idx = blockIdx.x * 512 + threadIdx.x;
  if (idx < WC_ELEMS) {
    int e  = idx & 7;
    int j  = (idx >> 3) & 511;
    int kc = (idx >> 12) & 3;
    int ks = idx >> 14;
    int c  = ks * 32 + kc * 8 + e;
    float v = (c < 1024) ? W1t[j * 1024 + c] : W1p[j * 320 + (c - 1024)];
    Wc[idx] = f2bf(v);
  }
  if (idx < W2C_ELEMS) {
    int e  = idx & 7;
    int ko = (idx >> 3) & 31;
    int jc = idx >> 8;
    int j  = jc * 8 + e;
    float v = (ko < KOUT) ? W2[ko * 512 + j] : 0.0f;
    W2c[idx] = f2bf(v);
  }
  if (idx < 512) bc[idx]  = b1t[idx] + b1p[idx];
  if (idx < 32)  b2c[idx] = (idx < KOUT) ? b2[idx] : 0.0f;
}

// ---------------------------------------------------------------------------
// 256 blocks x 512 threads (8 waves, 1 block/CU). Block tile 128 x 512.
// Wave w: wm=w>>2 rows wm*64+[0,64), wn=w&3 cols wn*128+[0,128):
// acc[4 mi][8 ni] f32x4 = 128 VGPR.
// LDS: A dbuf [2][4kc][128row][8] @0      (16 KB)
//      B dbuf [2][4kc][512 j][8]  @16384  (64 KB, gls-linear)
//      phase2 h-chunk [16pl][128r][8] @0  (32 KB, aliases after loop)
// Total 80 KB.
// ---------------------------------------------------------------------------
__global__ __launch_bounds__(512, 2) void joint_kernel(
    const float* __restrict__ f, const float* __restrict__ g,
    const unsigned short* __restrict__ Wc, const unsigned short* __restrict__ W2c,
    const float* __restrict__ bc, const float* __restrict__ b2c,
    float* __restrict__ out) {
  __shared__ __align__(16) char smem[81920];

  const int tid = threadIdx.x;
  const int l   = tid & 63;
  const int w   = tid >> 6;          // wave 0..7
  const int wm  = w >> 2;            // 0..1 (rows wm*64)
  const int wn  = w & 3;             // 0..3 (cols wn*128)
  const int m0  = blockIdx.x * 128;

  const int kcg = l >> 4;            // 0..3
  const int lc  = l & 15;

  // A staging mapping: per half h (64 rows): row = h*64 + (tid>>3),
  // k-float-offset = (tid&7)*4 -> frag kc=(tid&7)>>1, byte sub=(tid&1)*8.
  const int rW   = tid >> 3;                  // 0..63
  const int koff = (tid & 7) * 4;             // 0,4,..,28
  const char* fA0 = (const char*)f + (size_t)(m0 + rW) * 4096 + koff * 4;
  const char* fA1 = (const char*)f + (size_t)(m0 + 64 + rW) * 4096 + koff * 4;
  const char* gA0 = (const char*)g + (size_t)(m0 + rW) * 1280 + koff * 4;
  const char* gA1 = (const char*)g + (size_t)(m0 + 64 + rW) * 1280 + koff * 4;
  const unsigned awr0 = (unsigned)(((tid & 7) >> 1) * 2048 + rW * 16 + (tid & 1) * 8);
  const unsigned awr1 = awr0 + 1024;          // rows +64 -> +64*16 B

  f32x4 acc[4][8];
#pragma unroll
  for (int mi = 0; mi < 4; mi++)
#pragma unroll
    for (int ni = 0; ni < 8; ni++) acc[mi][ni] = (f32x4)(0.0f);

  f32x4 pEv0, pEv1, pOd0, pOd1;     // A prefetch reg sets (issue/cons ping)

#define GLSB(T, NXT) {                                                      \
    const char* bs_ = (const char*)Wc + (size_t)(T) * 32768 + tid * 16;     \
    char* bd_ = smem + 16384 + (NXT) * 32768 + tid * 16;                    \
    gls16(bs_,          bd_);                                               \
    gls16(bs_ +  8192,  bd_ +  8192);                                       \
    gls16(bs_ + 16384,  bd_ + 16384);                                       \
    gls16(bs_ + 24576,  bd_ + 24576);                                       \
  }

#define WRA(NXT, R0, R1) {                                                  \
    s16x4 h0_, h1_;                                                         \
    h0_[0] = (short)f2bf(R0[0]); h0_[1] = (short)f2bf(R0[1]);               \
    h0_[2] = (short)f2bf(R0[2]); h0_[3] = (short)f2bf(R0[3]);               \
    h1_[0] = (short)f2bf(R1[0]); h1_[1] = (short)f2bf(R1[1]);               \
    h1_[2] = (short)f2bf(R1[2]); h1_[3] = (short)f2bf(R1[3]);               \
    *(s16x4*)(smem + (NXT) * 8192 + awr0) = h0_;                            \
    *(s16x4*)(smem + (NXT) * 8192 + awr1) = h1_;                            \
  }

  // One K-step: two barrier-paired phases of 16 MFMA.
  // phA: gls B(T+1) + write A(T+1) + ds_read {A mi0-3, B ni0-3}; bar; mfma.
  // phB: issue A(T+2) regs + ds_read {B ni4-7}; VMCNT(2); bar; mfma.
#define K_STEP(T, BUF, NXT, C0, C1, I0, I1, PF0, PF1, DO_ST, DO_ISS, VMA) { \
    s16x8 af_[4]; s16x8 ba_[4]; s16x8 bb_[4];                               \
    if (DO_ST) { GLSB((T) + 1, NXT); WRA(NXT, C0, C1); }                    \
    _Pragma("unroll")                                                       \
    for (int mi = 0; mi < 4; mi++)                                          \
      af_[mi] = *(const s16x8*)(smem + (BUF) * 8192 + kcg * 2048 +          \
                                (wm * 64 + mi * 16 + lc) * 16);             \
    _Pragma("unroll")                                                       \
    for (int ni = 0; ni < 4; ni++)                                          \
      ba_[ni] = *(const s16x8*)(smem + 16384 + (BUF) * 32768 + kcg * 8192 + \
                                (wn * 128 + ni * 16 + lc) * 16);            \
    SBAR();                                                                 \
    LGKM0();                                                                \
    PRIO(1);                                                                \
    _Pragma("unroll")                                                       \
    for (int mi = 0; mi < 4; mi++)                                          \
      _Pragma("unroll")                                                     \
      for (int ni = 0; ni < 4; ni++)                                        \
        acc[mi][ni] = __builtin_amdgcn_mfma_f32_16x16x32_bf16(              \
            af_[mi], ba_[ni], acc[mi][ni], 0, 0, 0);                        \
    PRIO(0);                                                                \
    SBAR();                                                                 \
    if (DO_ISS) { I0 = *(const f32x4*)(PF0); I1 = *(const f32x4*)(PF1); }   \
    _Pragma("unroll")                                                       \
    for (int ni = 0; ni < 4; ni++)                                          \
      bb_[ni] = *(const s16x8*)(smem + 16384 + (BUF) * 32768 + kcg * 8192 + \
                                (wn * 128 + (4 + ni) * 16 + lc) * 16);      \
    VMA;                                                                    \
    SBAR();                                                                 \
    LGKM0();                                                                \
    PRIO(1);                                                                \
    _Pragma("unroll")                                                       \
    for (int mi = 0; mi < 4; mi++)                                          \
      _Pragma("unroll")                                                     \
      for (int ni = 0; ni < 4; ni++)                                        \
        acc[mi][4 + ni] = __builtin_amdgcn_mfma_f32_16x16x32_bf16(          \
            af_[mi], bb_[ni], acc[mi][4 + ni], 0, 0, 0);                    \
    PRIO(0);                                                                \
    SBAR();                                                                 \
  }

  // ---- prologue: gls B(0)->buf0; A(0) temp + A(1)->pOd; write A(0) ----
  GLSB(0, 0);
  {
    f32x4 t0 = *(const f32x4*)(fA0);
    f32x4 t1 = *(const f32x4*)(fA1);
    pOd0 = *(const f32x4*)(fA0 + 128);
    pOd1 = *(const f32x4*)(fA1 + 128);
    WRA(0, t0, t1);                  // compiler vmcnt(2): waits B(0)+A(0)
  }
  VMCNT(2);                          // leave A(1) in flight
  LGKM0();
  SBAR();

  // ---- K loop: T=0..29 (A src f), T=30..39 (A src g), tail 40,41 ----
  for (int T = 0; T < 30; T += 2) {
    K_STEP(T,     0, 1, pOd0, pOd1, pEv0, pEv1,
           fA0 + (T + 2) * 128, fA1 + (T + 2) * 128, 1, 1, VMCNT(2));
    K_STEP(T + 1, 1, 0, pEv0, pEv1, pOd0, pOd1,
           fA0 + (T + 3) * 128, fA1 + (T + 3) * 128, 1, 1, VMCNT(2));
  }
  for (int T = 30; T < 40; T += 2) {
    K_STEP(T,     0, 1, pOd0, pOd1, pEv0, pEv1,
           gA0 + (T - 30) * 128, gA1 + (T - 30) * 128, 1, 1, VMCNT(2));
    K_STEP(T + 1, 1, 0, pEv0, pEv1, pOd0, pOd1,
           gA0 + (T - 29) * 128, gA1 + (T - 29) * 128, 1, 1, VMCNT(2));
  }
  K_STEP(40, 0, 1, pOd0, pOd1, pEv0, pEv1, fA0, fA1, 1, 0, VMCNT(0));
  K_STEP(41, 1, 0, pEv0, pEv1, pOd0, pOd1, fA0, fA1, 0, 0, );

  // ---- phase 2: y = relu(h+bias) @ W2^T + b2, h in 4 col-chunks ----
  // Chunk p: cols [p*128,(p+1)*128), written by waves wn==p (wm 0,1).
  // Consumers: wave w owns y rows w*16..w*16+15, both ko-tiles.
  float bias[8];
#pragma unroll
  for (int ni = 0; ni < 8; ni++) bias[ni] = bc[wn * 128 + ni * 16 + lc];

  f32x4 acc2a = (f32x4)(0.0f);
  f32x4 acc2b = (f32x4)(0.0f);
  const unsigned h_rdrow = (unsigned)((w * 16 + lc) * 16);

#pragma unroll
  for (int p = 0; p < 4; p++) {
    __syncthreads();                 // h chunk region free
    if (wn == p) {
#pragma unroll
      for (int ni = 0; ni < 8; ni++) {
        const int jrel  = ni * 16 + lc;          // 0..127
        const int plane = jrel >> 3;             // 0..15
        const unsigned wswz = (unsigned)((plane & 3) << 5);
#pragma unroll
        for (int mi = 0; mi < 4; mi++)
#pragma unroll
          for (int r = 0; r < 4; r++) {
            float v = fmaxf(acc[mi][ni][r] + bias[ni], 0.0f);
            const unsigned rowh = (unsigned)(wm * 64 + mi * 16 + kcg * 4 + r);
            *(unsigned short*)(smem + plane * 2048 +
                ((rowh * 16 + (jrel & 7) * 2) ^ wswz)) = f2bf(v);
          }
      }
    }
    __syncthreads();
#pragma unroll
    for (int ks2 = 0; ks2 < 4; ks2++) {
      const int plane = ks2 * 4 + kcg;
      s16x8 hf = *(const s16x8*)(smem + plane * 2048 +
                                 (h_rdrow ^ ((unsigned)(plane & 3) << 5)));
      s16x8 w0 = *(const s16x8*)((const char*)W2c + (p * 16 + plane) * 512 + lc * 16);
      s16x8 w1 = *(const s16x8*)((const char*)W2c + (p * 16 + plane) * 512 + (16 + lc) * 16);
      acc2a = __builtin_amdgcn_mfma_f32_16x16x32_bf16(hf, w0, acc2a, 0, 0, 0);
      acc2b = __builtin_amdgcn_mfma_f32_16x16x32_bf16(hf, w1, acc2b, 0, 0, 0);
    }
  }

  // ---- epilogue: +b2, store (29 of 32 cols) ----
  {
    const float bb0 = b2c[lc];
    const float bb1 = b2c[16 + lc];
    const int orow0 = m0 + w * 16 + kcg * 4;
#pragma unroll
    for (int r = 0; r < 4; r++) {
      const size_t row = (size_t)(orow0 + r);
      out[row * KOUT + lc] = acc2a[r] + bb0;
      if (lc < KOUT - 16) out[row * KOUT + 16 + lc] = acc2b[r] + bb1;
    }
  }

#undef GLSB
#undef WRA
#undef K_STEP
}

// ---------------------------------------------------------------------------
extern "C" void kernel_launch(void* const* d_in, const int* in_sizes, int n_in,
                              void* d_out, int out_size, void* d_ws, size_t ws_size,
                              hipStream_t stream) {
  const float* f   = (const float*)d_in[0];
  const float* g   = (const float*)d_in[1];
  const float* W1t = (const float*)d_in[2];
  const float* b1t = (const float*)d_in[3];
  const float* W1p = (const float*)d_in[4];
  const float* b1p = (const float*)d_in[5];
  const float* W2  = (const float*)d_in[6];
  const float* b2  = (const float*)d_in[7];
  float* out = (float*)d_out;

  unsigned short* Wc  = (unsigned short*)d_ws;
  unsigned short* W2c = Wc + WC_ELEMS;
  float* bcp  = (float*)(W2c + W2C_ELEMS);
  float* b2cp = bcp + 512;

  prep_kernel<<<WC_ELEMS / 512, 512, 0, stream>>>(W1t, b1t, W1p, b1p, W2, b2,
                                                  Wc, W2c, bcp, b2cp);
  joint_kernel<<<N_ROWS / 128, 512, 0, stream>>>(f, g, Wc, W2c, bcp, b2cp, out);
}

// Round 12
// 80.230 us; speedup vs baseline: 1.9961x; 1.0362x over previous
//
#include <hip/hip_runtime.h>

// ---------------------------------------------------------------------------
// Joint network: y = relu(f@W1t^T + g@W1p^T + (b1t+b1p)) @ W2^T + b2
// N=32768, K1=1344 (1024 f + 320 g), J=512, KOUT=29. fp32 in/out, bf16 MFMA.
// R12: K-WINDOW=64 with FULL double-buffering (fixes R11's cross-wave vmcnt
//      bug). Per window: stage entire next B window (64 KB gls) + next A
//      (reg), compute 64 MFMA/wave, ONE drain+barrier (vmcnt0+lgkm0+sbar).
//      LDS = A dbuf 32K + B dbuf 128K = 160 KiB. 21 windows (was 42 steps).
// ---------------------------------------------------------------------------

typedef float  f32x4  __attribute__((ext_vector_type(4)));
typedef short  s16x8  __attribute__((ext_vector_type(8)));   // 8 bf16

#define N_ROWS   32768
#define KOUT     29

#define WC_ELEMS   (42 * 4 * 512 * 8)    // 688128 bf16: [chunk42][kc4][j512][8]
#define W2C_ELEMS  (64 * 32 * 8)         // 16384 bf16:  [jc][ko32][8]

#define VMCNT0()   asm volatile("s_waitcnt vmcnt(0)" ::: "memory")
#define LGKM0()    asm volatile("s_waitcnt lgkmcnt(0)" ::: "memory")
#define SBAR()     __builtin_amdgcn_s_barrier()
#define PRIO(n)    __builtin_amdgcn_s_setprio(n)

typedef const __attribute__((address_space(1))) unsigned int* gp_t;
typedef __attribute__((address_space(3))) unsigned int* lp_t;

static __device__ __forceinline__ void gls16(const void* g, void* l) {
  __builtin_amdgcn_global_load_lds((gp_t)g, (lp_t)l, 16, 0, 0);
}

static __device__ __forceinline__ unsigned short f2bf(float x) {
  union { float f; unsigned u; } v; v.f = x;
  unsigned r = v.u + 0x7fffu + ((v.u >> 16) & 1u);   // RNE
  return (unsigned short)(r >> 16);
}

// ---------------------------------------------------------------------------
__global__ __launch_bounds__(512) void prep_kernel(
    const float* __restrict__ W1t, const float* __restrict__ b1t,
    const float* __restrict__ W1p, const float* __restrict__ b1p,
    const float* __restrict__ W2,  const float* __restrict__ b2,
    unsigned short* __restrict__ Wc, unsigned short* __restrict__ W2c,
    float* __restrict__ bc, float* __restrict__ b2c) {
  int idx = blockIdx.x * 512 + threadIdx.x;
  if (idx < WC_ELEMS) {
    int e  = idx & 7;
    int j  = (idx >> 3) & 511;
    int kc = (idx >> 12) & 3;
    int ks = idx >> 14;
    int c  = ks * 32 + kc * 8 + e;
    float v = (c < 1024) ? W1t[j * 1024 + c] : W1p[j * 320 + (c - 1024)];
    Wc[idx] = f2bf(v);
  }
  if (idx < W2C_ELEMS) {
    int e  = idx & 7;
    int ko = (idx >> 3) & 31;
    int jc = idx >> 8;
    int j  = jc * 8 + e;
    float v = (ko < KOUT) ? W2[ko * 512 + j] : 0.0f;
    W2c[idx] = f2bf(v);
  }
  if (idx < 512) bc[idx]  = b1t[idx] + b1p[idx];
  if (idx < 32)  b2c[idx] = (idx < KOUT) ? b2[idx] : 0.0f;
}

// ---------------------------------------------------------------------------
// 256 blocks x 512 threads (8 waves, 1 block/CU). Block tile 128 x 512.
// Wave w: wm=w>>2 rows wm*64+[0,64), wn=w&3 cols wn*128+[0,128).
// LDS: A dbuf [2][8kc][128row][8] @0       (32 KB, XOR-swizzled)
//      B dbuf [2][2sub][4kc][512j][8] @32768 (128 KB, gls-linear)
//      phase2 h-chunk [16pl][128r][8] @0   (32 KB, aliases A)
// Total 163840 B = 160 KiB (hardware max).
// ---------------------------------------------------------------------------
__global__ __launch_bounds__(512, 2) void joint_kernel(
    const float* __restrict__ f, const float* __restrict__ g,
    const unsigned short* __restrict__ Wc, const unsigned short* __restrict__ W2c,
    const float* __restrict__ bc, const float* __restrict__ b2c,
    float* __restrict__ out) {
  __shared__ __align__(16) char smem[163840];

  const int tid = threadIdx.x;
  const int l   = tid & 63;
  const int w   = tid >> 6;          // wave 0..7
  const int wm  = w >> 2;            // 0..1 (rows wm*64)
  const int wn  = w & 3;             // 0..3 (cols wn*128)
  const int m0  = blockIdx.x * 128;

  const int kcg = l >> 4;            // 0..3
  const int lc  = l & 15;

  // ---- A staging thread map: row = tid>>2 (128), q = tid&3 ----
  // Thread stages k=[q*16,q*16+16) of its row per 64-K window:
  // 4 f32x4 loads -> 2 s16x8 b128-writes to kc planes 2q, 2q+1 (XOR swz).
  const int rowW = tid >> 2;
  const int q    = tid & 3;
  const char* fAth = (const char*)f + (size_t)(m0 + rowW) * 4096 + q * 64;
  const char* gAth = (const char*)g + (size_t)(m0 + rowW) * 1280 + q * 64;
  const unsigned awr0 = (unsigned)((2 * q)     * 2048 + ((rowW * 16) ^ ((2 * q)     << 5)));
  const unsigned awr1 = (unsigned)((2 * q + 1) * 2048 + ((rowW * 16) ^ ((2 * q + 1) << 5)));

  // ---- A fragment read bases (sub-a: kc=kcg; sub-b: kc=kcg+4) ----
  const unsigned a0base = (unsigned)(kcg * 2048 + wm * 1024 + ((lc * 16) ^ (kcg << 5)));
  const unsigned a1base = (unsigned)((kcg + 4) * 2048 + wm * 1024 + ((lc * 16) ^ ((kcg + 4) << 5)));
  // ---- B fragment read base within a 32-K sub-image ----
  const unsigned b_rd = (unsigned)(kcg * 8192 + (wn * 128 + lc) * 16);

  f32x4 acc[4][8];
#pragma unroll
  for (int mi = 0; mi < 4; mi++)
#pragma unroll
    for (int ni = 0; ni < 8; ni++) acc[mi][ni] = (f32x4)(0.0f);

  f32x4 pE0, pE1, pE2, pE3;          // A prefetch set E (even windows' PN)
  f32x4 pO0, pO1, pO2, pO3;          // A prefetch set O

  // Stage B 64-K window WN into buffer WN&1 (64 KB, 8 x gls16/thread).
#define GLSB64(WN) {                                                        \
    const char* bs_ = (const char*)Wc + (size_t)(WN) * 65536 + tid * 16;    \
    char* bd_ = smem + 32768 + (size_t)((WN) & 1) * 65536 + tid * 16;       \
    gls16(bs_,          bd_);                                               \
    gls16(bs_ +  8192,  bd_ +  8192);                                       \
    gls16(bs_ + 16384,  bd_ + 16384);                                       \
    gls16(bs_ + 24576,  bd_ + 24576);                                       \
    gls16(bs_ + 32768,  bd_ + 32768);                                       \
    gls16(bs_ + 40960,  bd_ + 40960);                                       \
    gls16(bs_ + 49152,  bd_ + 49152);                                       \
    gls16(bs_ + 57344,  bd_ + 57344);                                       \
  }

#define WRA(AB, R0, R1, R2, R3) {                                           \
    s16x8 h0_, h1_;                                                         \
    h0_[0] = (short)f2bf(R0[0]); h0_[1] = (short)f2bf(R0[1]);               \
    h0_[2] = (short)f2bf(R0[2]); h0_[3] = (short)f2bf(R0[3]);               \
    h0_[4] = (short)f2bf(R1[0]); h0_[5] = (short)f2bf(R1[1]);               \
    h0_[6] = (short)f2bf(R1[2]); h0_[7] = (short)f2bf(R1[3]);               \
    h1_[0] = (short)f2bf(R2[0]); h1_[1] = (short)f2bf(R2[1]);               \
    h1_[2] = (short)f2bf(R2[2]); h1_[3] = (short)f2bf(R2[3]);               \
    h1_[4] = (short)f2bf(R3[0]); h1_[5] = (short)f2bf(R3[1]);               \
    h1_[6] = (short)f2bf(R3[2]); h1_[7] = (short)f2bf(R3[3]);               \
    *(s16x8*)(smem + (AB) * 16384 + awr0) = h0_;                            \
    *(s16x8*)(smem + (AB) * 16384 + awr1) = h1_;                            \
  }

  // Window W: stage B(W+1) + load A(W+2) regs; compute 64 MFMA from bufs
  // W&1; stage A(W+1) from PC; full drain + ONE barrier. All LDS produced
  // in window W is consumed only after the barrier => cross-wave safe.
#define WINDOW(W, PC0, PC1, PC2, PC3, PN0, PN1, PN2, PN3, ASRC, G, AI, WR) { \
    if (G)  { GLSB64((W) + 1); }                                            \
    if (AI) { PN0 = *(const f32x4*)(ASRC);                                  \
              PN1 = *(const f32x4*)((ASRC) + 16);                           \
              PN2 = *(const f32x4*)((ASRC) + 32);                           \
              PN3 = *(const f32x4*)((ASRC) + 48); }                         \
    {                                                                       \
      const unsigned ab_ = ((unsigned)(W) & 1u) * 16384u;                   \
      const unsigned bb_ = 32768u + ((unsigned)(W) & 1u) * 65536u;          \
      s16x8 af_[4]; s16x8 bq_[8];                                           \
      _Pragma("unroll")                                                     \
      for (int mi = 0; mi < 4; mi++)                                        \
        af_[mi] = *(const s16x8*)(smem + ab_ + a0base + mi * 256);          \
      _Pragma("unroll")                                                     \
      for (int ni = 0; ni < 8; ni++)                                        \
        bq_[ni] = *(const s16x8*)(smem + bb_ + b_rd + ni * 256);            \
      PRIO(1);                                                              \
      _Pragma("unroll")                                                     \
      for (int mi = 0; mi < 4; mi++)                                        \
        _Pragma("unroll")                                                   \
        for (int ni = 0; ni < 8; ni++)                                      \
          acc[mi][ni] = __builtin_amdgcn_mfma_f32_16x16x32_bf16(            \
              af_[mi], bq_[ni], acc[mi][ni], 0, 0, 0);                      \
      PRIO(0);                                                              \
      _Pragma("unroll")                                                     \
      for (int mi = 0; mi < 4; mi++)                                        \
        af_[mi] = *(const s16x8*)(smem + ab_ + a1base + mi * 256);          \
      _Pragma("unroll")                                                     \
      for (int ni = 0; ni < 8; ni++)                                        \
        bq_[ni] = *(const s16x8*)(smem + bb_ + 32768u + b_rd + ni * 256);   \
      PRIO(1);                                                              \
      _Pragma("unroll")                                                     \
      for (int mi = 0; mi < 4; mi++)                                        \
        _Pragma("unroll")                                                   \
        for (int ni = 0; ni < 8; ni++)                                      \
          acc[mi][ni] = __builtin_amdgcn_mfma_f32_16x16x32_bf16(            \
              af_[mi], bq_[ni], acc[mi][ni], 0, 0, 0);                      \
      PRIO(0);                                                              \
    }                                                                       \
    if (WR) { WRA((((W) & 1) ^ 1), PC0, PC1, PC2, PC3); }                   \
    VMCNT0();                                                               \
    LGKM0();                                                                \
    SBAR();                                                                 \
  }

  // ---- prologue: gls B window 0; A(0)->pE, A(1)->pO; stage A(0) ----
  GLSB64(0);
  pE0 = *(const f32x4*)(fAth);
  pE1 = *(const f32x4*)(fAth + 16);
  pE2 = *(const f32x4*)(fAth + 32);
  pE3 = *(const f32x4*)(fAth + 48);
  pO0 = *(const f32x4*)(fAth + 256);
  pO1 = *(const f32x4*)(fAth + 272);
  pO2 = *(const f32x4*)(fAth + 288);
  pO3 = *(const f32x4*)(fAth + 304);
  WRA(0, pE0, pE1, pE2, pE3);
  VMCNT0();
  LGKM0();
  SBAR();

  // ---- windows 0..13: A(W+2) from f (c = 2..15) ----
  for (int W = 0; W < 14; W += 2) {
    WINDOW(W,     pO0, pO1, pO2, pO3, pE0, pE1, pE2, pE3,
           fAth + (size_t)(W + 2) * 256, 1, 1, 1);
    WINDOW(W + 1, pE0, pE1, pE2, pE3, pO0, pO1, pO2, pO3,
           fAth + (size_t)(W + 3) * 256, 1, 1, 1);
  }
  // ---- windows 14..18: A(W+2) from g (c-16 = 0..4) ----
  WINDOW(14, pO0, pO1, pO2, pO3, pE0, pE1, pE2, pE3, gAth,        1, 1, 1);
  WINDOW(15, pE0, pE1, pE2, pE3, pO0, pO1, pO2, pO3, gAth + 256,  1, 1, 1);
  WINDOW(16, pO0, pO1, pO2, pO3, pE0, pE1, pE2, pE3, gAth + 512,  1, 1, 1);
  WINDOW(17, pE0, pE1, pE2, pE3, pO0, pO1, pO2, pO3, gAth + 768,  1, 1, 1);
  WINDOW(18, pO0, pO1, pO2, pO3, pE0, pE1, pE2, pE3, gAth + 1024, 1, 1, 1);
  // ---- window 19: stage B(20) + A(20); no A issue ----
  WINDOW(19, pE0, pE1, pE2, pE3, pO0, pO1, pO2, pO3, gAth,        1, 0, 1);
  // ---- window 20: compute only ----
  WINDOW(20, pO0, pO1, pO2, pO3, pE0, pE1, pE2, pE3, gAth,        0, 0, 0);

  // ---- phase 2 (verified R10 structure): y = relu(h+bias) @ W2^T + b2 ----
  // Chunk p: cols [p*128,(p+1)*128), written by waves wn==p (wm 0,1).
  // Consumers: wave w owns y rows w*16..w*16+15, both ko-tiles.
  float bias[8];
#pragma unroll
  for (int ni = 0; ni < 8; ni++) bias[ni] = bc[wn * 128 + ni * 16 + lc];

  f32x4 acc2a = (f32x4)(0.0f);
  f32x4 acc2b = (f32x4)(0.0f);
  const unsigned h_rdrow = (unsigned)((w * 16 + lc) * 16);

#pragma unroll
  for (int p = 0; p < 4; p++) {
    __syncthreads();                 // h chunk region free
    if (wn == p) {
#pragma unroll
      for (int ni = 0; ni < 8; ni++) {
        const int jrel  = ni * 16 + lc;          // 0..127
        const int plane = jrel >> 3;             // 0..15
        const unsigned wswz = (unsigned)((plane & 3) << 5);
#pragma unroll
        for (int mi = 0; mi < 4; mi++)
#pragma unroll
          for (int r = 0; r < 4; r++) {
            float v = fmaxf(acc[mi][ni][r] + bias[ni], 0.0f);
            const unsigned rowh = (unsigned)(wm * 64 + mi * 16 + kcg * 4 + r);
            *(unsigned short*)(smem + plane * 2048 +
                ((rowh * 16 + (jrel & 7) * 2) ^ wswz)) = f2bf(v);
          }
      }
    }
    __syncthreads();
#pragma unroll
    for (int ks2 = 0; ks2 < 4; ks2++) {
      const int plane = ks2 * 4 + kcg;
      s16x8 hf = *(const s16x8*)(smem + plane * 2048 +
                                 (h_rdrow ^ ((unsigned)(plane & 3) << 5)));
      s16x8 w0 = *(const s16x8*)((const char*)W2c + (p * 16 + plane) * 512 + lc * 16);
      s16x8 w1 = *(const s16x8*)((const char*)W2c + (p * 16 + plane) * 512 + (16 + lc) * 16);
      acc2a = __builtin_amdgcn_mfma_f32_16x16x32_bf16(hf, w0, acc2a, 0, 0, 0);
      acc2b = __builtin_amdgcn_mfma_f32_16x16x32_bf16(hf, w1, acc2b, 0, 0, 0);
    }
  }

  // ---- epilogue: +b2, store (29 of 32 cols) ----
  {
    const float bb0 = b2c[lc];
    const float bb1 = b2c[16 + lc];
    const int orow0 = m0 + w * 16 + kcg * 4;
#pragma unroll
    for (int r = 0; r < 4; r++) {
      const size_t row = (size_t)(orow0 + r);
      out[row * KOUT + lc] = acc2a[r] + bb0;
      if (lc < KOUT - 16) out[row * KOUT + 16 + lc] = acc2b[r] + bb1;
    }
  }

#undef GLSB64
#undef WRA
#undef WINDOW
}

// ---------------------------------------------------------------------------
extern "C" void kernel_launch(void* const* d_in, const int* in_sizes, int n_in,
                              void* d_out, int out_size, void* d_ws, size_t ws_size,
                              hipStream_t stream) {
  const float* f   = (const float*)d_in[0];
  const float* g   = (const float*)d_in[1];
  const float* W1t = (const float*)d_in[2];
  const float* b1t = (const float*)d_in[3];
  const float* W1p = (const float*)d_in[4];
  const float* b1p = (const float*)d_in[5];
  const float* W2  = (const float*)d_in[6];
  const float* b2  = (const float*)d_in[7];
  float* out = (float*)d_out;

  unsigned short* Wc  = (unsigned short*)d_ws;
  unsigned short* W2c = Wc + WC_ELEMS;
  float* bcp  = (float*)(W2c + W2C_ELEMS);
  float* b2cp = bcp + 512;

  prep_kernel<<<WC_ELEMS / 512, 512, 0, stream>>>(W1t, b1t, W1p, b1p, W2, b2,
                                                  Wc, W2c, bcp, b2cp);
  joint_kernel<<<N_ROWS / 128, 512, 0, stream>>>(f, g, Wc, W2c, bcp, b2cp, out);
}

// Round 13
// 62.415 us; speedup vs baseline: 2.5658x; 1.2854x over previous
//
#include <hip/hip_runtime.h>

// ---------------------------------------------------------------------------
// Joint network: y = relu(f@W1t^T + g@W1p^T + (b1t+b1p)) @ W2^T + b2
// N=32768, K1=1344 (1024 f + 320 g), J=512, KOUT=29. fp32 in/out, bf16 MFMA.
// R13: R12 (K-window=64, full dbuf, 21 barriers) minus the spill:
//      SINGLE A-prefetch set (16 VGPR) loaded at window start, staged at
//      window end. B via gls (reg-free). Peak ~84 VGPR + 128 acc.
// ---------------------------------------------------------------------------

typedef float  f32x4  __attribute__((ext_vector_type(4)));
typedef short  s16x8  __attribute__((ext_vector_type(8)));   // 8 bf16

#define N_ROWS   32768
#define KOUT     29

#define WC_ELEMS   (42 * 4 * 512 * 8)    // 688128 bf16: [chunk42][kc4][j512][8]
#define W2C_ELEMS  (64 * 32 * 8)         // 16384 bf16:  [jc][ko32][8]

#define VMCNT0()   asm volatile("s_waitcnt vmcnt(0)" ::: "memory")
#define LGKM0()    asm volatile("s_waitcnt lgkmcnt(0)" ::: "memory")
#define SBAR()     __builtin_amdgcn_s_barrier()
#define PRIO(n)    __builtin_amdgcn_s_setprio(n)

typedef const __attribute__((address_space(1))) unsigned int* gp_t;
typedef __attribute__((address_space(3))) unsigned int* lp_t;

static __device__ __forceinline__ void gls16(const void* g, void* l) {
  __builtin_amdgcn_global_load_lds((gp_t)g, (lp_t)l, 16, 0, 0);
}

static __device__ __forceinline__ unsigned short f2bf(float x) {
  union { float f; unsigned u; } v; v.f = x;
  unsigned r = v.u + 0x7fffu + ((v.u >> 16) & 1u);   // RNE
  return (unsigned short)(r >> 16);
}

// ---------------------------------------------------------------------------
__global__ __launch_bounds__(512) void prep_kernel(
    const float* __restrict__ W1t, const float* __restrict__ b1t,
    const float* __restrict__ W1p, const float* __restrict__ b1p,
    const float* __restrict__ W2,  const float* __restrict__ b2,
    unsigned short* __restrict__ Wc, unsigned short* __restrict__ W2c,
    float* __restrict__ bc, float* __restrict__ b2c) {
  int idx = blockIdx.x * 512 + threadIdx.x;
  if (idx < WC_ELEMS) {
    int e  = idx & 7;
    int j  = (idx >> 3) & 511;
    int kc = (idx >> 12) & 3;
    int ks = idx >> 14;
    int c  = ks * 32 + kc * 8 + e;
    float v = (c < 1024) ? W1t[j * 1024 + c] : W1p[j * 320 + (c - 1024)];
    Wc[idx] = f2bf(v);
  }
  if (idx < W2C_ELEMS) {
    int e  = idx & 7;
    int ko = (idx >> 3) & 31;
    int jc = idx >> 8;
    int j  = jc * 8 + e;
    float v = (ko < KOUT) ? W2[ko * 512 + j] : 0.0f;
    W2c[idx] = f2bf(v);
  }
  if (idx < 512) bc[idx]  = b1t[idx] + b1p[idx];
  if (idx < 32)  b2c[idx] = (idx < KOUT) ? b2[idx] : 0.0f;
}

// ---------------------------------------------------------------------------
// 256 blocks x 512 threads (8 waves, 1 block/CU). Block tile 128 x 512.
// Wave w: wm=w>>2 rows wm*64+[0,64), wn=w&3 cols wn*128+[0,128).
// LDS: A dbuf [2][8kc][128row][8] @0         (32 KB, XOR-swizzled)
//      B dbuf [2][2sub][4kc][512j][8] @32768 (128 KB, gls-linear)
//      phase2 h-chunk [16pl][128r][8] @0     (32 KB, aliases A)
// Total 163840 B = 160 KiB.
// ---------------------------------------------------------------------------
__global__ __launch_bounds__(512, 2) void joint_kernel(
    const float* __restrict__ f, const float* __restrict__ g,
    const unsigned short* __restrict__ Wc, const unsigned short* __restrict__ W2c,
    const float* __restrict__ bc, const float* __restrict__ b2c,
    float* __restrict__ out) {
  __shared__ __align__(16) char smem[163840];

  const int tid = threadIdx.x;
  const int l   = tid & 63;
  const int w   = tid >> 6;          // wave 0..7
  const int wm  = w >> 2;            // 0..1 (rows wm*64)
  const int wn  = w & 3;             // 0..3 (cols wn*128)
  const int m0  = blockIdx.x * 128;

  const int kcg = l >> 4;            // 0..3
  const int lc  = l & 15;

  // A staging map: row = tid>>2 (128), q = tid&3; thread stages
  // k=[q*16,q*16+16) of its row per 64-K window -> kc planes 2q, 2q+1.
  const int rowW = tid >> 2;
  const int q    = tid & 3;
  const char* fAth = (const char*)f + (size_t)(m0 + rowW) * 4096 + q * 64;
  const char* gAth = (const char*)g + (size_t)(m0 + rowW) * 1280 + q * 64;
  const unsigned awr0 = (unsigned)((2 * q)     * 2048 + ((rowW * 16) ^ ((2 * q)     << 5)));
  const unsigned awr1 = (unsigned)((2 * q + 1) * 2048 + ((rowW * 16) ^ ((2 * q + 1) << 5)));

  // A fragment read bases (sub-a: kc=kcg; sub-b: kc=kcg+4)
  const unsigned a0base = (unsigned)(kcg * 2048 + wm * 1024 + ((lc * 16) ^ (kcg << 5)));
  const unsigned a1base = (unsigned)((kcg + 4) * 2048 + wm * 1024 + ((lc * 16) ^ ((kcg + 4) << 5)));
  // B fragment read base within a 32-K sub-image
  const unsigned b_rd = (unsigned)(kcg * 8192 + (wn * 128 + lc) * 16);

  f32x4 acc[4][8];
#pragma unroll
  for (int mi = 0; mi < 4; mi++)
#pragma unroll
    for (int ni = 0; ni < 8; ni++) acc[mi][ni] = (f32x4)(0.0f);

  f32x4 pN0, pN1, pN2, pN3;          // the ONLY A prefetch set (16 VGPR)

#define GLSB64(WN) {                                                        \
    const char* bs_ = (const char*)Wc + (size_t)(WN) * 65536 + tid * 16;    \
    char* bd_ = smem + 32768 + (size_t)((WN) & 1) * 65536 + tid * 16;       \
    gls16(bs_,          bd_);                                               \
    gls16(bs_ +  8192,  bd_ +  8192);                                       \
    gls16(bs_ + 16384,  bd_ + 16384);                                       \
    gls16(bs_ + 24576,  bd_ + 24576);                                       \
    gls16(bs_ + 32768,  bd_ + 32768);                                       \
    gls16(bs_ + 40960,  bd_ + 40960);                                       \
    gls16(bs_ + 49152,  bd_ + 49152);                                       \
    gls16(bs_ + 57344,  bd_ + 57344);                                       \
  }

#define WRA(AB) {                                                           \
    s16x8 h0_, h1_;                                                         \
    h0_[0] = (short)f2bf(pN0[0]); h0_[1] = (short)f2bf(pN0[1]);             \
    h0_[2] = (short)f2bf(pN0[2]); h0_[3] = (short)f2bf(pN0[3]);             \
    h0_[4] = (short)f2bf(pN1[0]); h0_[5] = (short)f2bf(pN1[1]);             \
    h0_[6] = (short)f2bf(pN1[2]); h0_[7] = (short)f2bf(pN1[3]);             \
    h1_[0] = (short)f2bf(pN2[0]); h1_[1] = (short)f2bf(pN2[1]);             \
    h1_[2] = (short)f2bf(pN2[2]); h1_[3] = (short)f2bf(pN2[3]);             \
    h1_[4] = (short)f2bf(pN3[0]); h1_[5] = (short)f2bf(pN3[1]);             \
    h1_[6] = (short)f2bf(pN3[2]); h1_[7] = (short)f2bf(pN3[3]);             \
    *(s16x8*)(smem + (AB) * 16384 + awr0) = h0_;                            \
    *(s16x8*)(smem + (AB) * 16384 + awr1) = h1_;                            \
  }

  // Window W: stage B(W+1) (gls) + load A(W+1) regs at start; compute
  // 64 MFMA/wave from buffers W&1; write A(W+1) to buffer (W&1)^1;
  // full drain + ONE barrier. All producer->consumer edges cross the
  // barrier => cross-wave safe by construction.
#define WINDOW(W, ASRC, G, AI, WR) {                                        \
    if (G)  { GLSB64((W) + 1); }                                            \
    if (AI) { pN0 = *(const f32x4*)(ASRC);                                  \
              pN1 = *(const f32x4*)((ASRC) + 16);                           \
              pN2 = *(const f32x4*)((ASRC) + 32);                           \
              pN3 = *(const f32x4*)((ASRC) + 48); }                         \
    {                                                                       \
      const unsigned ab_ = ((unsigned)(W) & 1u) * 16384u;                   \
      const unsigned bb_ = 32768u + ((unsigned)(W) & 1u) * 65536u;          \
      s16x8 af_[4]; s16x8 bq_[8];                                           \
      _Pragma("unroll")                                                     \
      for (int mi = 0; mi < 4; mi++)                                        \
        af_[mi] = *(const s16x8*)(smem + ab_ + a0base + mi * 256);          \
      _Pragma("unroll")                                                     \
      for (int ni = 0; ni < 8; ni++)                                        \
        bq_[ni] = *(const s16x8*)(smem + bb_ + b_rd + ni * 256);            \
      PRIO(1);                                                              \
      _Pragma("unroll")                                                     \
      for (int mi = 0; mi < 4; mi++)                                        \
        _Pragma("unroll")                                                   \
        for (int ni = 0; ni < 8; ni++)                                      \
          acc[mi][ni] = __builtin_amdgcn_mfma_f32_16x16x32_bf16(            \
              af_[mi], bq_[ni], acc[mi][ni], 0, 0, 0);                      \
      PRIO(0);                                                              \
      _Pragma("unroll")                                                     \
      for (int mi = 0; mi < 4; mi++)                                        \
        af_[mi] = *(const s16x8*)(smem + ab_ + a1base + mi * 256);          \
      _Pragma("unroll")                                                     \
      for (int ni = 0; ni < 8; ni++)                                        \
        bq_[ni] = *(const s16x8*)(smem + bb_ + 32768u + b_rd + ni * 256);   \
      PRIO(1);                                                              \
      _Pragma("unroll")                                                     \
      for (int mi = 0; mi < 4; mi++)                                        \
        _Pragma("unroll")                                                   \
        for (int ni = 0; ni < 8; ni++)                                      \
          acc[mi][ni] = __builtin_amdgcn_mfma_f32_16x16x32_bf16(            \
              af_[mi], bq_[ni], acc[mi][ni], 0, 0, 0);                      \
      PRIO(0);                                                              \
    }                                                                       \
    if (WR) { WRA((((W) & 1) ^ 1)); }                                       \
    VMCNT0();                                                               \
    LGKM0();                                                                \
    SBAR();                                                                 \
  }

  // ---- prologue: gls B(0); A(0)->pN; stage A(0) into buf0; drain ----
  GLSB64(0);
  pN0 = *(const f32x4*)(fAth);
  pN1 = *(const f32x4*)(fAth + 16);
  pN2 = *(const f32x4*)(fAth + 32);
  pN3 = *(const f32x4*)(fAth + 48);
  WRA(0);
  VMCNT0();
  LGKM0();
  SBAR();

  // ---- windows 0..14: load A(W+1) from f (chunks 1..15) ----
  for (int W = 0; W < 14; W += 2) {
    WINDOW(W,     fAth + (size_t)(W + 1) * 256, 1, 1, 1);
    WINDOW(W + 1, fAth + (size_t)(W + 2) * 256, 1, 1, 1);
  }
  WINDOW(14, fAth + 15 * 256, 1, 1, 1);
  // ---- windows 15..19: load A(W+1) from g (chunks 0..4) ----
  WINDOW(15, gAth,        1, 1, 1);
  WINDOW(16, gAth + 256,  1, 1, 1);
  WINDOW(17, gAth + 512,  1, 1, 1);
  WINDOW(18, gAth + 768,  1, 1, 1);
  WINDOW(19, gAth + 1024, 1, 1, 1);
  // ---- window 20: compute only ----
  WINDOW(20, gAth, 0, 0, 0);

  // ---- phase 2 (verified structure): y = relu(h+bias) @ W2^T + b2 ----
  // Chunk p: cols [p*128,(p+1)*128), written by waves wn==p (wm 0,1).
  // Consumers: wave w owns y rows w*16..w*16+15, both ko-tiles.
  float bias[8];
#pragma unroll
  for (int ni = 0; ni < 8; ni++) bias[ni] = bc[wn * 128 + ni * 16 + lc];

  f32x4 acc2a = (f32x4)(0.0f);
  f32x4 acc2b = (f32x4)(0.0f);
  const unsigned h_rdrow = (unsigned)((w * 16 + lc) * 16);

#pragma unroll
  for (int p = 0; p < 4; p++) {
    __syncthreads();                 // h chunk region free
    if (wn == p) {
#pragma unroll
      for (int ni = 0; ni < 8; ni++) {
        const int jrel  = ni * 16 + lc;          // 0..127
        const int plane = jrel >> 3;             // 0..15
        const unsigned wswz = (unsigned)((plane & 3) << 5);
#pragma unroll
        for (int mi = 0; mi < 4; mi++)
#pragma unroll
          for (int r = 0; r < 4; r++) {
            float v = fmaxf(acc[mi][ni][r] + bias[ni], 0.0f);
            const unsigned rowh = (unsigned)(wm * 64 + mi * 16 + kcg * 4 + r);
            *(unsigned short*)(smem + plane * 2048 +
                ((rowh * 16 + (jrel & 7) * 2) ^ wswz)) = f2bf(v);
          }
      }
    }
    __syncthreads();
#pragma unroll
    for (int ks2 = 0; ks2 < 4; ks2++) {
      const int plane = ks2 * 4 + kcg;
      s16x8 hf = *(const s16x8*)(smem + plane * 2048 +
                                 (h_rdrow ^ ((unsigned)(plane & 3) << 5)));
      s16x8 w0 = *(const s16x8*)((const char*)W2c + (p * 16 + plane) * 512 + lc * 16);
      s16x8 w1 = *(const s16x8*)((const char*)W2c + (p * 16 + plane) * 512 + (16 + lc) * 16);
      acc2a = __builtin_amdgcn_mfma_f32_16x16x32_bf16(hf, w0, acc2a, 0, 0, 0);
      acc2b = __builtin_amdgcn_mfma_f32_16x16x32_bf16(hf, w1, acc2b, 0, 0, 0);
    }
  }

  // ---- epilogue: +b2, store (29 of 32 cols) ----
  {
    const float bb0 = b2c[lc];
    const float bb1 = b2c[16 + lc];
    const int orow0 = m0 + w * 16 + kcg * 4;
#pragma unroll
    for (int r = 0; r < 4; r++) {
      const size_t row = (size_t)(orow0 + r);
      out[row * KOUT + lc] = acc2a[r] + bb0;
      if (lc < KOUT - 16) out[row * KOUT + 16 + lc] = acc2b[r] + bb1;
    }
  }

#undef GLSB64
#undef WRA
#undef WINDOW
}

// ---------------------------------------------------------------------------
extern "C" void kernel_launch(void* const* d_in, const int* in_sizes, int n_in,
                              void* d_out, int out_size, void* d_ws, size_t ws_size,
                              hipStream_t stream) {
  const float* f   = (const float*)d_in[0];
  const float* g   = (const float*)d_in[1];
  const float* W1t = (const float*)d_in[2];
  const float* b1t = (const float*)d_in[3];
  const float* W1p = (const float*)d_in[4];
  const float* b1p = (const float*)d_in[5];
  const float* W2  = (const float*)d_in[6];
  const float* b2  = (const float*)d_in[7];
  float* out = (float*)d_out;

  unsigned short* Wc  = (unsigned short*)d_ws;
  unsigned short* W2c = Wc + WC_ELEMS;
  float* bcp  = (float*)(W2c + W2C_ELEMS);
  float* b2cp = bcp + 512;

  prep_kernel<<<WC_ELEMS / 512, 512, 0, stream>>>(W1t, b1t, W1p, b1p, W2, b2,
                                                  Wc, W2c, bcp, b2cp);
  joint_kernel<<<N_ROWS / 128, 512, 0, stream>>>(f, g, Wc, W2c, bcp, b2cp, out);
}